// Round 6
// baseline (57.230 us; speedup 1.0000x reference)
//
#include <hip/hip_runtime.h>
#include <hip/hip_bf16.h>
#include <stdint.h>

// MNISTQuant: out[65536,50] = x[65536,784] @ (int8_w[784,50] * scaler)
// R6: R5 + nontemporal (streaming) x loads and out stores. x is read exactly
// once chip-wide and out written once -> zero reuse at any cache level, so
// bypassing cache-allocate overhead is free upside. Core structure unchanged:
// wave-owns-tile, kappa-permuted fragment mapping (contiguous 64B per row per
// load), fragment-order dequantized B table in LDS, depth-6 named-register
// prefetch, barrier-free steady state, per-wave LDS out staging.

typedef __attribute__((ext_vector_type(8))) short bf16x8;
typedef __attribute__((ext_vector_type(4))) float f32x4;

#define IN_F 784
#define OUT_F 50
#define NSTEP 25              // K padded 784 -> 800 (25 x 32)
#define NCT 4                 // col tiles (50 -> 64)
#define NBLK 256              // 1 block/CU
#define NTHREADS 1024         // 16 waves, 1 tile per wave

__device__ __forceinline__ short f2bf(float f) {
    return (short)__builtin_bit_cast(unsigned short, __float2bfloat16(f));
}

__device__ __forceinline__ f32x4 ldnt(const float* p) {
    return __builtin_nontemporal_load((const f32x4*)p);
}

__global__ __launch_bounds__(NTHREADS, 4) void MNISTQuant_48687749267957_kernel(
    const float* __restrict__ x,
    const int* __restrict__ wq,          // int8 weights delivered as int32
    const float* __restrict__ scaler,
    float* __restrict__ out)
{
    __shared__ bf16x8 bfl[NCT * NSTEP * 64];      // 102,400 B fragment table
    __shared__ float  ostage[16][16 * OUT_F];     //  51,200 B out staging
    // wq staging overlays ostage (39,200 B); dead after prologue barrier #2
    signed char* w8 = (signed char*)&ostage[0][0];

    const int tid  = threadIdx.x;
    const int lane = tid & 63;
    const int wave = tid >> 6;
    const int arow = lane & 15;          // A row (m) within tile
    const int kgrp = lane >> 4;
    const float scl = scaler[0];

    // k-permutation: hw slot (s, kgrp, j) holds logical
    //   kappa = s*32 + kgrp*4 + j            (j<4,  from pa: row bytes [s*128, s*128+64))
    //   kappa = s*32 + 16 + kgrp*4 + (j-4)   (j>=4, from pb: row bytes [s*128+64, s*128+128))
    // B-table built with the same kappa -> result invariant.

    const int tile = blockIdx.x * 16 + wave;
    const float* xr = x + (size_t)tile * (16 * IN_F) + (size_t)arow * IN_F + kgrp * 4;

    // ---- issue depth-6 x prefetch FIRST (named registers, nontemporal) ----
    f32x4 p0a = ldnt(xr +   0), p0b = ldnt(xr +  16);
    f32x4 p1a = ldnt(xr +  32), p1b = ldnt(xr +  48);
    f32x4 p2a = ldnt(xr +  64), p2b = ldnt(xr +  80);
    f32x4 p3a = ldnt(xr +  96), p3b = ldnt(xr + 112);
    f32x4 p4a = ldnt(xr + 128), p4b = ldnt(xr + 144);
    f32x4 p5a = ldnt(xr + 160), p5b = ldnt(xr + 176);

    // ---- Prologue A: stage wq into LDS, coalesced int4 ----
    for (int i = tid; i < (IN_F * OUT_F) / 4; i += NTHREADS) {   // 9800/4 = 2450
        const int4 v = ((const int4*)wq)[i];
        unsigned int packed = (v.x & 255) | ((v.y & 255) << 8) |
                              ((v.z & 255) << 16) | (((unsigned int)v.w) << 24);
        ((unsigned int*)w8)[i] = packed;
    }
    __syncthreads();

    // ---- Prologue B: fragment-order dequantized B table (kappa mapping) ----
    for (int g = tid; g < NCT * NSTEP * 64; g += NTHREADS) {
        const int l   = g & 63;
        const int cs  = g >> 6;
        const int ct  = cs / NSTEP;
        const int s   = cs - ct * NSTEP;
        const int col = ct * 16 + (l & 15);
        const int kg  = l >> 4;
        const int k0  = s * 32 + kg * 4;         // j<4: k0+j   (always < 784)
        const int k1  = k0 + 16;                 // j>=4: k1+(j-4) (OOB iff s==24)
        bf16x8 f;
        #pragma unroll
        for (int j = 0; j < 4; ++j) {
            float w = (col < OUT_F) ? (float)w8[(k0 + j) * OUT_F + col] * scl : 0.f;
            f[j] = f2bf(w);
        }
        #pragma unroll
        for (int j = 0; j < 4; ++j) {
            float w = (col < OUT_F && s < NSTEP - 1)
                        ? (float)w8[(k1 + j) * OUT_F + col] * scl : 0.f;
            f[4 + j] = f2bf(w);
        }
        bfl[g] = f;
    }
    __syncthreads();   // w8 dead; bfl read-only; ostage free for epilogue

    // two base pointers so all ds_read offsets fit 16-bit immediates
    const bf16x8* bw_lo = bfl + lane;                     // ct 0,1
    const bf16x8* bw_hi = bfl + 2 * NSTEP * 64 + lane;    // ct 2,3

    f32x4 acc0 = {0.f,0.f,0.f,0.f}, acc1 = {0.f,0.f,0.f,0.f};
    f32x4 acc2 = {0.f,0.f,0.f,0.f}, acc3 = {0.f,0.f,0.f,0.f};

    #define STEP(P, S)                                                             \
    {                                                                              \
        bf16x8 a;                                                                  \
        a[0]=f2bf(P##a.x); a[1]=f2bf(P##a.y); a[2]=f2bf(P##a.z); a[3]=f2bf(P##a.w);\
        a[4]=f2bf(P##b.x); a[5]=f2bf(P##b.y); a[6]=f2bf(P##b.z); a[7]=f2bf(P##b.w);\
        if ((S) + 6 < NSTEP - 1) {                                                 \
            P##a = ldnt(xr + ((S) + 6) * 32);                                      \
            P##b = ldnt(xr + ((S) + 6) * 32 + 16);                                 \
        } else if ((S) + 6 == NSTEP - 1) {                                         \
            P##a = ldnt(xr + (NSTEP - 1) * 32);   /* k 768..783 only */            \
        }                                                                          \
        acc0 = __builtin_amdgcn_mfma_f32_16x16x32_bf16(a, bw_lo[(0*NSTEP+(S))*64], acc0, 0, 0, 0); \
        acc1 = __builtin_amdgcn_mfma_f32_16x16x32_bf16(a, bw_lo[(1*NSTEP+(S))*64], acc1, 0, 0, 0); \
        acc2 = __builtin_amdgcn_mfma_f32_16x16x32_bf16(a, bw_hi[(0*NSTEP+(S))*64], acc2, 0, 0, 0); \
        acc3 = __builtin_amdgcn_mfma_f32_16x16x32_bf16(a, bw_hi[(1*NSTEP+(S))*64], acc3, 0, 0, 0); \
    }

    #pragma unroll
    for (int g = 0; g < 4; ++g) {        // steps 0..23, depth-6 rotation
        const int s0 = g * 6;
        STEP(p0, s0 + 0)
        STEP(p1, s0 + 1)
        STEP(p2, s0 + 2)
        STEP(p3, s0 + 3)
        STEP(p4, s0 + 4)
        STEP(p5, s0 + 5)
    }
    {   // tail step 24: pa real (k 768..783), upper half zero
        bf16x8 a;
        a[0]=f2bf(p0a.x); a[1]=f2bf(p0a.y); a[2]=f2bf(p0a.z); a[3]=f2bf(p0a.w);
        a[4]=0; a[5]=0; a[6]=0; a[7]=0;
        acc0 = __builtin_amdgcn_mfma_f32_16x16x32_bf16(a, bw_lo[(0*NSTEP+24)*64], acc0, 0, 0, 0);
        acc1 = __builtin_amdgcn_mfma_f32_16x16x32_bf16(a, bw_lo[(1*NSTEP+24)*64], acc1, 0, 0, 0);
        acc2 = __builtin_amdgcn_mfma_f32_16x16x32_bf16(a, bw_hi[(0*NSTEP+24)*64], acc2, 0, 0, 0);
        acc3 = __builtin_amdgcn_mfma_f32_16x16x32_bf16(a, bw_hi[(1*NSTEP+24)*64], acc3, 0, 0, 0);
    }
    #undef STEP

    // ---- per-wave out staging (same-wave ds ordering, no barrier) ----
    float* ob = ostage[wave];
    #define STORECT(ACC, CT)                                              \
    {                                                                     \
        const int col = (CT) * 16 + arow;     /* C col = lane&15 */       \
        if (col < OUT_F) {                                                \
            _Pragma("unroll")                                             \
            for (int j = 0; j < 4; ++j)       /* C row = (lane>>4)*4+j */ \
                ob[(kgrp * 4 + j) * OUT_F + col] = ACC[j];                \
        }                                                                 \
    }
    STORECT(acc0, 0) STORECT(acc1, 1) STORECT(acc2, 2) STORECT(acc3, 3)
    #undef STORECT

    float* og = out + (size_t)tile * (16 * OUT_F);
    #pragma unroll
    for (int r = 0; r < 4; ++r) {
        const int idx = lane + r * 64;
        if (idx < (16 * OUT_F) / 4) {
            const f32x4 v = *((const f32x4*)ob + idx);
            __builtin_nontemporal_store(v, (f32x4*)og + idx);
        }
    }
}

extern "C" void kernel_launch(void* const* d_in, const int* in_sizes, int n_in,
                              void* d_out, int out_size, void* d_ws, size_t ws_size,
                              hipStream_t stream) {
    const float* x      = (const float*)d_in[0];
    const int*   wq     = (const int*)d_in[1];
    const float* scaler = (const float*)d_in[2];
    float*       out    = (float*)d_out;
    MNISTQuant_48687749267957_kernel<<<NBLK, NTHREADS, 0, stream>>>(x, wq, scaler, out);
}

// Round 7
// 47.548 us; speedup vs baseline: 1.2036x; 1.2036x over previous
//
#include <hip/hip_runtime.h>
#include <hip/hip_bf16.h>
#include <stdint.h>

// MNISTQuant: out[65536,50] = x[65536,784] @ (int8_w[784,50] * scaler)
// R7: R5 structure (champion, 43.5 us) with nt loads REVERTED (R6 showed
// no-allocate forfeits L3 service of x across replays: 43.5 -> 57.2 us)
// and the B-table built directly from global wq (L2-resident 157 KB;
// coalesced quarter-wave gathers) -- deletes the wq->LDS staging pass and
// one barrier. Wave-owns-tile, kappa-permuted contiguous-64B loads,
// depth-6 named-register prefetch, barrier-free steady state, per-wave
// LDS out staging. All registers named (no rule-#20 scratch).

typedef __attribute__((ext_vector_type(8))) short bf16x8;
typedef __attribute__((ext_vector_type(4))) float f32x4;

#define IN_F 784
#define OUT_F 50
#define NSTEP 25              // K padded 784 -> 800 (25 x 32)
#define NCT 4                 // col tiles (50 -> 64)
#define NBLK 256              // 1 block/CU
#define NTHREADS 1024         // 16 waves, 1 tile per wave

__device__ __forceinline__ short f2bf(float f) {
    return (short)__builtin_bit_cast(unsigned short, __float2bfloat16(f));
}

__global__ __launch_bounds__(NTHREADS, 4) void MNISTQuant_48687749267957_kernel(
    const float* __restrict__ x,
    const int* __restrict__ wq,          // int8 weights delivered as int32
    const float* __restrict__ scaler,
    float* __restrict__ out)
{
    __shared__ bf16x8 bfl[NCT * NSTEP * 64];      // 102,400 B fragment table
    __shared__ float  ostage[16][16 * OUT_F];     //  51,200 B out staging

    const int tid  = threadIdx.x;
    const int lane = tid & 63;
    const int wave = tid >> 6;
    const int arow = lane & 15;          // A row (m) within tile
    const int kgrp = lane >> 4;
    const float scl = scaler[0];

    // k-permutation: hw slot (s, kgrp, j) holds logical
    //   kappa = s*32 + kgrp*4 + j            (j<4,  from pa: row bytes [s*128, s*128+64))
    //   kappa = s*32 + 16 + kgrp*4 + (j-4)   (j>=4, from pb: row bytes [s*128+64, s*128+128))
    // B-table built with the same kappa -> result invariant.

    const int tile = blockIdx.x * 16 + wave;
    const float* xr = x + (size_t)tile * (16 * IN_F) + (size_t)arow * IN_F + kgrp * 4;

    // ---- issue depth-6 x prefetch FIRST (named registers) ----
    f32x4 p0a = *(const f32x4*)(xr +   0), p0b = *(const f32x4*)(xr +  16);
    f32x4 p1a = *(const f32x4*)(xr +  32), p1b = *(const f32x4*)(xr +  48);
    f32x4 p2a = *(const f32x4*)(xr +  64), p2b = *(const f32x4*)(xr +  80);
    f32x4 p3a = *(const f32x4*)(xr +  96), p3b = *(const f32x4*)(xr + 112);
    f32x4 p4a = *(const f32x4*)(xr + 128), p4b = *(const f32x4*)(xr + 144);
    f32x4 p5a = *(const f32x4*)(xr + 160), p5b = *(const f32x4*)(xr + 176);

    // ---- Prologue: fragment-order dequantized B table, straight from global ----
    // frag g = (ct*25+s)*64 + l; lane-quarter reads 16 consecutive dwords of a
    // wq row (one 64-B line) -> coalesced L2-resident gathers, no LDS staging.
    for (int g = tid; g < NCT * NSTEP * 64; g += NTHREADS) {
        const int l   = g & 63;
        const int cs  = g >> 6;
        const int ct  = cs / NSTEP;
        const int s   = cs - ct * NSTEP;
        const int col = ct * 16 + (l & 15);
        const int kg  = l >> 4;
        const int k0  = s * 32 + kg * 4;         // j<4: k0+j   (always < 784)
        const int k1  = k0 + 16;                 // j>=4: k1+(j-4) (OOB iff s==24)
        const bool cok = (col < OUT_F);
        const int  cc  = cok ? col : 0;          // clamp address, zero value
        bf16x8 f;
        #pragma unroll
        for (int j = 0; j < 4; ++j) {
            float w = cok ? (float)wq[(k0 + j) * OUT_F + cc] * scl : 0.f;
            f[j] = f2bf(w);
        }
        const bool hok = cok && (s < NSTEP - 1);
        #pragma unroll
        for (int j = 0; j < 4; ++j) {
            float w = hok ? (float)wq[(k1 + j) * OUT_F + cc] * scl : 0.f;
            f[4 + j] = f2bf(w);
        }
        bfl[g] = f;
    }
    __syncthreads();   // only barrier; bfl read-only below

    // two base pointers so all ds_read offsets fit 16-bit immediates
    const bf16x8* bw_lo = bfl + lane;                     // ct 0,1
    const bf16x8* bw_hi = bfl + 2 * NSTEP * 64 + lane;    // ct 2,3

    f32x4 acc0 = {0.f,0.f,0.f,0.f}, acc1 = {0.f,0.f,0.f,0.f};
    f32x4 acc2 = {0.f,0.f,0.f,0.f}, acc3 = {0.f,0.f,0.f,0.f};

    #define STEP(P, S)                                                             \
    {                                                                              \
        bf16x8 a;                                                                  \
        a[0]=f2bf(P##a.x); a[1]=f2bf(P##a.y); a[2]=f2bf(P##a.z); a[3]=f2bf(P##a.w);\
        a[4]=f2bf(P##b.x); a[5]=f2bf(P##b.y); a[6]=f2bf(P##b.z); a[7]=f2bf(P##b.w);\
        if ((S) + 6 < NSTEP - 1) {                                                 \
            P##a = *(const f32x4*)(xr + ((S) + 6) * 32);                           \
            P##b = *(const f32x4*)(xr + ((S) + 6) * 32 + 16);                      \
        } else if ((S) + 6 == NSTEP - 1) {                                         \
            P##a = *(const f32x4*)(xr + (NSTEP - 1) * 32);  /* k 768..783 only */  \
        }                                                                          \
        acc0 = __builtin_amdgcn_mfma_f32_16x16x32_bf16(a, bw_lo[(0*NSTEP+(S))*64], acc0, 0, 0, 0); \
        acc1 = __builtin_amdgcn_mfma_f32_16x16x32_bf16(a, bw_lo[(1*NSTEP+(S))*64], acc1, 0, 0, 0); \
        acc2 = __builtin_amdgcn_mfma_f32_16x16x32_bf16(a, bw_hi[(0*NSTEP+(S))*64], acc2, 0, 0, 0); \
        acc3 = __builtin_amdgcn_mfma_f32_16x16x32_bf16(a, bw_hi[(1*NSTEP+(S))*64], acc3, 0, 0, 0); \
    }

    #pragma unroll
    for (int g = 0; g < 4; ++g) {        // steps 0..23, depth-6 rotation
        const int s0 = g * 6;
        STEP(p0, s0 + 0)
        STEP(p1, s0 + 1)
        STEP(p2, s0 + 2)
        STEP(p3, s0 + 3)
        STEP(p4, s0 + 4)
        STEP(p5, s0 + 5)
    }
    {   // tail step 24: pa real (k 768..783), upper half zero
        bf16x8 a;
        a[0]=f2bf(p0a.x); a[1]=f2bf(p0a.y); a[2]=f2bf(p0a.z); a[3]=f2bf(p0a.w);
        a[4]=0; a[5]=0; a[6]=0; a[7]=0;
        acc0 = __builtin_amdgcn_mfma_f32_16x16x32_bf16(a, bw_lo[(0*NSTEP+24)*64], acc0, 0, 0, 0);
        acc1 = __builtin_amdgcn_mfma_f32_16x16x32_bf16(a, bw_lo[(1*NSTEP+24)*64], acc1, 0, 0, 0);
        acc2 = __builtin_amdgcn_mfma_f32_16x16x32_bf16(a, bw_hi[(0*NSTEP+24)*64], acc2, 0, 0, 0);
        acc3 = __builtin_amdgcn_mfma_f32_16x16x32_bf16(a, bw_hi[(1*NSTEP+24)*64], acc3, 0, 0, 0);
    }
    #undef STEP

    // ---- per-wave out staging (same-wave ds ordering, no barrier) ----
    float* ob = ostage[wave];
    #define STORECT(ACC, CT)                                              \
    {                                                                     \
        const int col = (CT) * 16 + arow;     /* C col = lane&15 */       \
        if (col < OUT_F) {                                                \
            _Pragma("unroll")                                             \
            for (int j = 0; j < 4; ++j)       /* C row = (lane>>4)*4+j */ \
                ob[(kgrp * 4 + j) * OUT_F + col] = ACC[j];                \
        }                                                                 \
    }
    STORECT(acc0, 0) STORECT(acc1, 1) STORECT(acc2, 2) STORECT(acc3, 3)
    #undef STORECT

    float* og = out + (size_t)tile * (16 * OUT_F);
    #pragma unroll
    for (int r = 0; r < 4; ++r) {
        const int idx = lane + r * 64;
        if (idx < (16 * OUT_F) / 4)
            *((f32x4*)og + idx) = *((const f32x4*)ob + idx);
    }
}

extern "C" void kernel_launch(void* const* d_in, const int* in_sizes, int n_in,
                              void* d_out, int out_size, void* d_ws, size_t ws_size,
                              hipStream_t stream) {
    const float* x      = (const float*)d_in[0];
    const int*   wq     = (const int*)d_in[1];
    const float* scaler = (const float*)d_in[2];
    float*       out    = (float*)d_out;
    MNISTQuant_48687749267957_kernel<<<NBLK, NTHREADS, 0, stream>>>(x, wq, scaler, out);
}

// Round 8
// 43.724 us; speedup vs baseline: 1.3089x; 1.0875x over previous
//
#include <hip/hip_runtime.h>
#include <hip/hip_bf16.h>
#include <stdint.h>

// MNISTQuant: out[65536,50] = x[65536,784] @ (int8_w[784,50] * scaler)
// R8 = R5 verbatim (champion, 43.5 us). History of attempted deltas:
//  - R6 nontemporal loads/stores: 57.2 us (no-allocate forfeits L3 warmth
//    across graph replays) -> reverted.
//  - R7 B-table from global (no wq LDS stage): 47.5 us (scattered gathers
//    serialize worse than coalesced stage) -> reverted.
// Structure: wave-owns-tile (16 waves x 256 blocks x 16 rows), kappa-permuted
// fragment mapping so every x load is a contiguous 64 B per row, fragment-
// order dequantized B table in LDS (102.4 KB), depth-6 named-register global
// prefetch, barrier-free steady state, per-wave LDS out staging for
// contiguous f32x4 stores. All registers named (no rule-#20 scratch).
// Effective delivery 5.03 TB/s ~= 93% of best-observed read-heavy ceiling.

typedef __attribute__((ext_vector_type(8))) short bf16x8;
typedef __attribute__((ext_vector_type(4))) float f32x4;

#define IN_F 784
#define OUT_F 50
#define NSTEP 25              // K padded 784 -> 800 (25 x 32)
#define NCT 4                 // col tiles (50 -> 64)
#define NBLK 256              // 1 block/CU
#define NTHREADS 1024         // 16 waves, 1 tile per wave

__device__ __forceinline__ short f2bf(float f) {
    return (short)__builtin_bit_cast(unsigned short, __float2bfloat16(f));
}

__global__ __launch_bounds__(NTHREADS, 4) void MNISTQuant_48687749267957_kernel(
    const float* __restrict__ x,
    const int* __restrict__ wq,          // int8 weights delivered as int32
    const float* __restrict__ scaler,
    float* __restrict__ out)
{
    __shared__ bf16x8 bfl[NCT * NSTEP * 64];      // 102,400 B fragment table
    __shared__ float  ostage[16][16 * OUT_F];     //  51,200 B out staging
    // wq staging overlays ostage (39,200 B); dead after prologue barrier #2
    signed char* w8 = (signed char*)&ostage[0][0];

    const int tid  = threadIdx.x;
    const int lane = tid & 63;
    const int wave = tid >> 6;
    const int arow = lane & 15;          // A row (m) within tile
    const int kgrp = lane >> 4;
    const float scl = scaler[0];

    // k-permutation: hw slot (s, kgrp, j) holds logical
    //   kappa = s*32 + kgrp*4 + j            (j<4,  from pa: row bytes [s*128, s*128+64))
    //   kappa = s*32 + 16 + kgrp*4 + (j-4)   (j>=4, from pb: row bytes [s*128+64, s*128+128))
    // B-table built with the same kappa -> result invariant.

    const int tile = blockIdx.x * 16 + wave;
    const float* xr = x + (size_t)tile * (16 * IN_F) + (size_t)arow * IN_F + kgrp * 4;

    // ---- issue depth-6 x prefetch FIRST (named registers) ----
    f32x4 p0a = *(const f32x4*)(xr +   0), p0b = *(const f32x4*)(xr +  16);
    f32x4 p1a = *(const f32x4*)(xr +  32), p1b = *(const f32x4*)(xr +  48);
    f32x4 p2a = *(const f32x4*)(xr +  64), p2b = *(const f32x4*)(xr +  80);
    f32x4 p3a = *(const f32x4*)(xr +  96), p3b = *(const f32x4*)(xr + 112);
    f32x4 p4a = *(const f32x4*)(xr + 128), p4b = *(const f32x4*)(xr + 144);
    f32x4 p5a = *(const f32x4*)(xr + 160), p5b = *(const f32x4*)(xr + 176);

    // ---- Prologue A: stage wq into LDS, coalesced int4 ----
    for (int i = tid; i < (IN_F * OUT_F) / 4; i += NTHREADS) {   // 9800/4 = 2450
        const int4 v = ((const int4*)wq)[i];
        unsigned int packed = (v.x & 255) | ((v.y & 255) << 8) |
                              ((v.z & 255) << 16) | (((unsigned int)v.w) << 24);
        ((unsigned int*)w8)[i] = packed;
    }
    __syncthreads();

    // ---- Prologue B: fragment-order dequantized B table (kappa mapping) ----
    for (int g = tid; g < NCT * NSTEP * 64; g += NTHREADS) {
        const int l   = g & 63;
        const int cs  = g >> 6;
        const int ct  = cs / NSTEP;
        const int s   = cs - ct * NSTEP;
        const int col = ct * 16 + (l & 15);
        const int kg  = l >> 4;
        const int k0  = s * 32 + kg * 4;         // j<4: k0+j   (always < 784)
        const int k1  = k0 + 16;                 // j>=4: k1+(j-4) (OOB iff s==24)
        bf16x8 f;
        #pragma unroll
        for (int j = 0; j < 4; ++j) {
            float w = (col < OUT_F) ? (float)w8[(k0 + j) * OUT_F + col] * scl : 0.f;
            f[j] = f2bf(w);
        }
        #pragma unroll
        for (int j = 0; j < 4; ++j) {
            float w = (col < OUT_F && s < NSTEP - 1)
                        ? (float)w8[(k1 + j) * OUT_F + col] * scl : 0.f;
            f[4 + j] = f2bf(w);
        }
        bfl[g] = f;
    }
    __syncthreads();   // w8 dead; bfl read-only; ostage free for epilogue

    // two base pointers so all ds_read offsets fit 16-bit immediates
    const bf16x8* bw_lo = bfl + lane;                     // ct 0,1
    const bf16x8* bw_hi = bfl + 2 * NSTEP * 64 + lane;    // ct 2,3

    f32x4 acc0 = {0.f,0.f,0.f,0.f}, acc1 = {0.f,0.f,0.f,0.f};
    f32x4 acc2 = {0.f,0.f,0.f,0.f}, acc3 = {0.f,0.f,0.f,0.f};

    #define STEP(P, S)                                                             \
    {                                                                              \
        bf16x8 a;                                                                  \
        a[0]=f2bf(P##a.x); a[1]=f2bf(P##a.y); a[2]=f2bf(P##a.z); a[3]=f2bf(P##a.w);\
        a[4]=f2bf(P##b.x); a[5]=f2bf(P##b.y); a[6]=f2bf(P##b.z); a[7]=f2bf(P##b.w);\
        if ((S) + 6 < NSTEP - 1) {                                                 \
            P##a = *(const f32x4*)(xr + ((S) + 6) * 32);                           \
            P##b = *(const f32x4*)(xr + ((S) + 6) * 32 + 16);                      \
        } else if ((S) + 6 == NSTEP - 1) {                                         \
            P##a = *(const f32x4*)(xr + (NSTEP - 1) * 32);  /* k 768..783 only */  \
        }                                                                          \
        acc0 = __builtin_amdgcn_mfma_f32_16x16x32_bf16(a, bw_lo[(0*NSTEP+(S))*64], acc0, 0, 0, 0); \
        acc1 = __builtin_amdgcn_mfma_f32_16x16x32_bf16(a, bw_lo[(1*NSTEP+(S))*64], acc1, 0, 0, 0); \
        acc2 = __builtin_amdgcn_mfma_f32_16x16x32_bf16(a, bw_hi[(0*NSTEP+(S))*64], acc2, 0, 0, 0); \
        acc3 = __builtin_amdgcn_mfma_f32_16x16x32_bf16(a, bw_hi[(1*NSTEP+(S))*64], acc3, 0, 0, 0); \
    }

    #pragma unroll
    for (int g = 0; g < 4; ++g) {        // steps 0..23, depth-6 rotation
        const int s0 = g * 6;
        STEP(p0, s0 + 0)
        STEP(p1, s0 + 1)
        STEP(p2, s0 + 2)
        STEP(p3, s0 + 3)
        STEP(p4, s0 + 4)
        STEP(p5, s0 + 5)
    }
    {   // tail step 24: pa real (k 768..783), upper half zero
        bf16x8 a;
        a[0]=f2bf(p0a.x); a[1]=f2bf(p0a.y); a[2]=f2bf(p0a.z); a[3]=f2bf(p0a.w);
        a[4]=0; a[5]=0; a[6]=0; a[7]=0;
        acc0 = __builtin_amdgcn_mfma_f32_16x16x32_bf16(a, bw_lo[(0*NSTEP+24)*64], acc0, 0, 0, 0);
        acc1 = __builtin_amdgcn_mfma_f32_16x16x32_bf16(a, bw_lo[(1*NSTEP+24)*64], acc1, 0, 0, 0);
        acc2 = __builtin_amdgcn_mfma_f32_16x16x32_bf16(a, bw_hi[(0*NSTEP+24)*64], acc2, 0, 0, 0);
        acc3 = __builtin_amdgcn_mfma_f32_16x16x32_bf16(a, bw_hi[(1*NSTEP+24)*64], acc3, 0, 0, 0);
    }
    #undef STEP

    // ---- per-wave out staging (same-wave ds ordering, no barrier) ----
    float* ob = ostage[wave];
    #define STORECT(ACC, CT)                                              \
    {                                                                     \
        const int col = (CT) * 16 + arow;     /* C col = lane&15 */       \
        if (col < OUT_F) {                                                \
            _Pragma("unroll")                                             \
            for (int j = 0; j < 4; ++j)       /* C row = (lane>>4)*4+j */ \
                ob[(kgrp * 4 + j) * OUT_F + col] = ACC[j];                \
        }                                                                 \
    }
    STORECT(acc0, 0) STORECT(acc1, 1) STORECT(acc2, 2) STORECT(acc3, 3)
    #undef STORECT

    float* og = out + (size_t)tile * (16 * OUT_F);
    #pragma unroll
    for (int r = 0; r < 4; ++r) {
        const int idx = lane + r * 64;
        if (idx < (16 * OUT_F) / 4)
            *((f32x4*)og + idx) = *((const f32x4*)ob + idx);
    }
}

extern "C" void kernel_launch(void* const* d_in, const int* in_sizes, int n_in,
                              void* d_out, int out_size, void* d_ws, size_t ws_size,
                              hipStream_t stream) {
    const float* x      = (const float*)d_in[0];
    const int*   wq     = (const int*)d_in[1];
    const float* scaler = (const float*)d_in[2];
    float*       out    = (float*)d_out;
    MNISTQuant_48687749267957_kernel<<<NBLK, NTHREADS, 0, stream>>>(x, wq, scaler, out);
}